// Round 1
// baseline (5069.905 us; speedup 1.0000x reference)
//
#include <hip/hip_runtime.h>

#define N_ROWS 10000
#define DIM    768
#define NCLS   1000
#define KNB    10
#define NITER  20
#define EPSV   1e-8f
#define JSPLIT 16
#define NTILES 157      // ceil(10000/64)
#define TOPK_TPB 10     // j-tiles per split (16*10 >= 157)
#define MAXE   2048

// ---------------- row normalize ----------------
__global__ __launch_bounds__(256) void rownorm_k(const float* __restrict__ feat,
                                                 float* __restrict__ nf) {
    int row = blockIdx.x;
    const float4* src = (const float4*)(feat + (size_t)row * DIM);
    int t = threadIdx.x;
    float4 v = make_float4(0.f, 0.f, 0.f, 0.f);
    float ss = 0.f;
    if (t < DIM / 4) { v = src[t]; ss = v.x*v.x + v.y*v.y + v.z*v.z + v.w*v.w; }
#pragma unroll
    for (int m = 1; m < 64; m <<= 1) ss += __shfl_xor(ss, m, 64);
    __shared__ float red[4];
    if ((t & 63) == 0) red[t >> 6] = ss;
    __syncthreads();
    float tot = red[0] + red[1] + red[2] + red[3];
    float inv = 1.0f / (sqrtf(tot) + EPSV);
    if (t < DIM / 4) {
        float4 o = make_float4(v.x*inv, v.y*inv, v.z*inv, v.w*inv);
        ((float4*)(nf + (size_t)row * DIM))[t] = o;
    }
}

// ---------------- generic C = A * B^T (64x64 tiles, 4x4/thread) ----------------
__global__ __launch_bounds__(256) void gemm_nt_k(const float* __restrict__ A,
                                                 const float* __restrict__ B,
                                                 float* __restrict__ Cout,
                                                 int M, int Nc) {
    __shared__ __align__(16) float As[16][64];
    __shared__ __align__(16) float Bs[16][64];
    int tid = threadIdx.x;
    int tx = tid & 15, ty = tid >> 4;
    int m0 = blockIdx.x * 64, n0 = blockIdx.y * 64;
    int lr = tid >> 2;            // 0..63 row staged by this thread
    int lk = (tid & 3) << 2;      // k sub-offset 0/4/8/12
    float acc[4][4];
#pragma unroll
    for (int i = 0; i < 4; ++i)
#pragma unroll
        for (int j = 0; j < 4; ++j) acc[i][j] = 0.f;

    int ar = m0 + lr, br = n0 + lr;
    bool aval = ar < M, bval = br < Nc;
    const float* arow = A + (size_t)ar * DIM + lk;
    const float* brow = B + (size_t)br * DIM + lk;
    float4 pa = aval ? *(const float4*)(arow) : make_float4(0,0,0,0);
    float4 pb = bval ? *(const float4*)(brow) : make_float4(0,0,0,0);

    for (int ch = 0; ch < DIM / 16; ++ch) {
        __syncthreads();
        As[lk+0][lr] = pa.x; As[lk+1][lr] = pa.y; As[lk+2][lr] = pa.z; As[lk+3][lr] = pa.w;
        Bs[lk+0][lr] = pb.x; Bs[lk+1][lr] = pb.y; Bs[lk+2][lr] = pb.z; Bs[lk+3][lr] = pb.w;
        __syncthreads();
        if (ch + 1 < DIM / 16) {
            int k0 = (ch + 1) * 16;
            pa = aval ? *(const float4*)(arow + k0) : make_float4(0,0,0,0);
            pb = bval ? *(const float4*)(brow + k0) : make_float4(0,0,0,0);
        }
#pragma unroll
        for (int kk = 0; kk < 16; ++kk) {
            float4 a4 = *(const float4*)(&As[kk][ty << 2]);
            float4 b4 = *(const float4*)(&Bs[kk][tx << 2]);
            float av[4] = {a4.x, a4.y, a4.z, a4.w};
            float bv[4] = {b4.x, b4.y, b4.z, b4.w};
#pragma unroll
            for (int i = 0; i < 4; ++i)
#pragma unroll
                for (int j = 0; j < 4; ++j) acc[i][j] = fmaf(av[i], bv[j], acc[i][j]);
        }
    }
#pragma unroll
    for (int i = 0; i < 4; ++i) {
        int r = m0 + (ty << 2) + i;
        if (r < M) {
#pragma unroll
            for (int j = 0; j < 4; ++j) {
                int c = n0 + (tx << 2) + j;
                if (c < Nc) Cout[(size_t)r * Nc + c] = acc[i][j];
            }
        }
    }
}

// ---------------- row softmax (C=1000) ----------------
__global__ __launch_bounds__(256) void softmax_k(const float* __restrict__ logits,
                                                 float* __restrict__ Y) {
    int row = blockIdx.x;
    const float* src = logits + (size_t)row * NCLS;
    __shared__ float sl[NCLS];
    __shared__ float red[4];
    int t = threadIdx.x;
    float mx = -1e30f;
    for (int c = t; c < NCLS; c += 256) { float x = src[c]; sl[c] = x; mx = fmaxf(mx, x); }
#pragma unroll
    for (int m = 1; m < 64; m <<= 1) mx = fmaxf(mx, __shfl_xor(mx, m, 64));
    if ((t & 63) == 0) red[t >> 6] = mx;
    __syncthreads();
    mx = fmaxf(fmaxf(red[0], red[1]), fmaxf(red[2], red[3]));
    float sum = 0.f;
    for (int c = t; c < NCLS; c += 256) { float e = expf(sl[c] - mx); sl[c] = e; sum += e; }
#pragma unroll
    for (int m = 1; m < 64; m <<= 1) sum += __shfl_xor(sum, m, 64);
    __syncthreads();
    if ((t & 63) == 0) red[t >> 6] = sum;
    __syncthreads();
    float inv = 1.0f / (red[0] + red[1] + red[2] + red[3]);
    float* dst = Y + (size_t)row * NCLS;
    for (int c = t; c < NCLS; c += 256) dst[c] = sl[c] * inv;
}

// ---------------- fused sims GEMM + per-row top-10 (partial over j-split) ----------------
__global__ __launch_bounds__(256) void simtopk_k(const float* __restrict__ nf,
                                                 float* __restrict__ pv,
                                                 int* __restrict__ pi_) {
    __shared__ __align__(16) float As[16][64];
    __shared__ __align__(16) float Bs[16][64];
    int tid = threadIdx.x;
    int tx = tid & 15, ty = tid >> 4;
    int m0 = blockIdx.x * 64;
    int js = blockIdx.y;
    int jt0 = js * TOPK_TPB;
    int jt1 = min(jt0 + TOPK_TPB, NTILES);
    int lr = tid >> 2;
    int lk = (tid & 3) << 2;

    float lv[4][10]; int li[4][10];
#pragma unroll
    for (int i = 0; i < 4; ++i)
#pragma unroll
        for (int s = 0; s < 10; ++s) { lv[i][s] = -1e30f; li[i][s] = 0x7fffffff; }

    int ar = m0 + lr;
    bool aval = ar < N_ROWS;
    const float* arow = nf + (size_t)ar * DIM + lk;

    for (int jt = jt0; jt < jt1; ++jt) {
        int n0 = jt * 64;
        int br = n0 + lr;
        bool bval = br < N_ROWS;
        const float* brow = nf + (size_t)br * DIM + lk;
        float acc[4][4];
#pragma unroll
        for (int i = 0; i < 4; ++i)
#pragma unroll
            for (int j = 0; j < 4; ++j) acc[i][j] = 0.f;

        float4 pa = aval ? *(const float4*)(arow) : make_float4(0,0,0,0);
        float4 pb = bval ? *(const float4*)(brow) : make_float4(0,0,0,0);
        for (int ch = 0; ch < DIM / 16; ++ch) {
            __syncthreads();
            As[lk+0][lr] = pa.x; As[lk+1][lr] = pa.y; As[lk+2][lr] = pa.z; As[lk+3][lr] = pa.w;
            Bs[lk+0][lr] = pb.x; Bs[lk+1][lr] = pb.y; Bs[lk+2][lr] = pb.z; Bs[lk+3][lr] = pb.w;
            __syncthreads();
            if (ch + 1 < DIM / 16) {
                int k0 = (ch + 1) * 16;
                pa = aval ? *(const float4*)(arow + k0) : make_float4(0,0,0,0);
                pb = bval ? *(const float4*)(brow + k0) : make_float4(0,0,0,0);
            }
#pragma unroll
            for (int kk = 0; kk < 16; ++kk) {
                float4 a4 = *(const float4*)(&As[kk][ty << 2]);
                float4 b4 = *(const float4*)(&Bs[kk][tx << 2]);
                float av[4] = {a4.x, a4.y, a4.z, a4.w};
                float bv[4] = {b4.x, b4.y, b4.z, b4.w};
#pragma unroll
                for (int i2 = 0; i2 < 4; ++i2)
#pragma unroll
                    for (int j2 = 0; j2 < 4; ++j2) acc[i2][j2] = fmaf(av[i2], bv[j2], acc[i2][j2]);
            }
        }
        // top-10 update (sorted-desc insert, fully static indexing -> registers)
#pragma unroll
        for (int i = 0; i < 4; ++i) {
            int row = m0 + (ty << 2) + i;
#pragma unroll
            for (int j = 0; j < 4; ++j) {
                int col = n0 + (tx << 2) + j;
                float val = acc[i][j];
                if (col < N_ROWS && col != row && val > lv[i][9]) {
                    lv[i][9] = val; li[i][9] = col;
#pragma unroll
                    for (int s = 9; s > 0; --s) {
                        if (lv[i][s] > lv[i][s-1]) {
                            float t2 = lv[i][s]; lv[i][s] = lv[i][s-1]; lv[i][s-1] = t2;
                            int   t3 = li[i][s]; li[i][s] = li[i][s-1]; li[i][s-1] = t3;
                        }
                    }
                }
            }
        }
    }
    // merge the 16 lanes sharing each row; write partial top-10 for this split
#pragma unroll
    for (int i = 0; i < 4; ++i) {
        int row = m0 + (ty << 2) + i;
        for (int sel = 0; sel < 10; ++sel) {
            float cv = lv[i][0]; int ci = li[i][0];
            float bv = cv; int bi = ci;
#pragma unroll
            for (int m = 8; m >= 1; m >>= 1) {
                float ov = __shfl_xor(bv, m, 16);
                int   oi = __shfl_xor(bi, m, 16);
                if (ov > bv || (ov == bv && oi < bi)) { bv = ov; bi = oi; }
            }
            if (tx == 0 && row < N_ROWS) {
                size_t o = ((size_t)js * N_ROWS + row) * KNB + sel;
                pv[o] = bv; pi_[o] = bi;
            }
            if (cv == bv && ci == bi) {   // I was the winner: pop my head
#pragma unroll
                for (int s = 0; s < 9; ++s) { lv[i][s] = lv[i][s+1]; li[i][s] = li[i][s+1]; }
                lv[i][9] = -1e30f; li[i][9] = 0x7fffffff;
            }
        }
    }
}

// ---------------- final merge of JSPLIT partial top-10 lists ----------------
__global__ void topmerge_k(float* __restrict__ pv, const int* __restrict__ pi_,
                           float* __restrict__ tv, int* __restrict__ ti_) {
    int row = blockIdx.x * blockDim.x + threadIdx.x;
    if (row >= N_ROWS) return;
    for (int sel = 0; sel < KNB; ++sel) {
        float best = -1e30f; long bslot = -1;
        for (int js = 0; js < JSPLIT; ++js) {
            size_t base = ((size_t)js * N_ROWS + row) * KNB;
            for (int k = 0; k < KNB; ++k) {
                float v = pv[base + k];
                if (v > best) { best = v; bslot = (long)(base + k); }
            }
        }
        tv[(size_t)row * KNB + sel] = best;
        ti_[(size_t)row * KNB + sel] = pi_[bslot];
        pv[bslot] = -1e30f;
    }
}

// ---------------- graph build ----------------
__global__ void edgecount_k(const float* __restrict__ tv, const int* __restrict__ ti_,
                            float* __restrict__ deg, int* __restrict__ cnt) {
    int e = blockIdx.x * blockDim.x + threadIdx.x;
    if (e >= N_ROWS * KNB) return;
    int i = e / KNB;
    int j = ti_[e];
    float v = fmaxf(tv[e], 0.f);
    float w = 0.5f * v * v * v;
    atomicAdd(&deg[i], w);
    atomicAdd(&deg[j], w);
    atomicAdd(&cnt[i], 1);
    atomicAdd(&cnt[j], 1);
}

__global__ __launch_bounds__(1024) void scan_k(const int* __restrict__ cnt,
                                               int* __restrict__ rowptr,
                                               int* __restrict__ cur,
                                               const float* __restrict__ deg,
                                               float* __restrict__ dis) {
    __shared__ int sb[1024];
    int t = threadIdx.x;
    int carry = 0;
    for (int base = 0; base < N_ROWS; base += 1024) {
        int idx = base + t;
        int x = (idx < N_ROWS) ? cnt[idx] : 0;
        sb[t] = x;
        __syncthreads();
        for (int offc = 1; offc < 1024; offc <<= 1) {
            int add = (t >= offc) ? sb[t - offc] : 0;
            __syncthreads();
            sb[t] += add;
            __syncthreads();
        }
        int incl = sb[t];
        int tot = sb[1023];
        if (idx < N_ROWS) {
            rowptr[idx + 1] = carry + incl;
            cur[idx] = carry + incl - x;
            if (idx == 0) rowptr[0] = 0;
            dis[idx] = 1.0f / (sqrtf(deg[idx] + EPSV));
        }
        __syncthreads();
        carry += tot;
    }
}

__global__ void fill_k(const float* __restrict__ tv, const int* __restrict__ ti_,
                       const float* __restrict__ dis, int* __restrict__ cur,
                       int* __restrict__ cols, float* __restrict__ wts) {
    int e = blockIdx.x * blockDim.x + threadIdx.x;
    if (e >= N_ROWS * KNB) return;
    int i = e / KNB;
    int j = ti_[e];
    float v = fmaxf(tv[e], 0.f);
    float w = 0.5f * v * v * v;
    float s = 0.99f * w * dis[i] * dis[j];   // ALPHA folded into edge weight
    int p1 = atomicAdd(&cur[i], 1); cols[p1] = j; wts[p1] = s;
    int p2 = atomicAdd(&cur[j], 1); cols[p2] = i; wts[p2] = s;
}

// ---------------- sparse propagation step ----------------
__global__ __launch_bounds__(256) void spmv_k(const int* __restrict__ rowptr,
                                              const int* __restrict__ cols,
                                              const float* __restrict__ wts,
                                              const float* __restrict__ Zin,
                                              const float* __restrict__ Y,
                                              float* __restrict__ Zout) {
    int i = blockIdx.x;
    int b = rowptr[i], e = rowptr[i + 1];
    int nnz = e - b;
    __shared__ int   cs[MAXE];
    __shared__ float wsh[MAXE];
    int nl = min(nnz, MAXE);
    for (int t = threadIdx.x; t < nl; t += 256) { cs[t] = cols[b + t]; wsh[t] = wts[b + t]; }
    __syncthreads();
    const float beta = (float)(1.0 - 0.99);
    for (int c = threadIdx.x; c < NCLS; c += 256) {
        float acc = beta * Y[(size_t)i * NCLS + c];
        for (int k = 0; k < nl; ++k) acc += wsh[k] * Zin[(size_t)cs[k] * NCLS + c];
        for (int k = MAXE; k < nnz; ++k) acc += wts[b + k] * Zin[(size_t)cols[b + k] * NCLS + c];
        Zout[(size_t)i * NCLS + c] = acc;
    }
}

extern "C" void kernel_launch(void* const* d_in, const int* in_sizes, int n_in,
                              void* d_out, int out_size, void* d_ws, size_t ws_size,
                              hipStream_t stream) {
    const float* feat = (const float*)d_in[0];
    const float* cw   = (const float*)d_in[1];
    float* out = (float*)d_out;
    char* ws = (char*)d_ws;
    size_t off = 0;
    auto alloc = [&](size_t b) { size_t o = off; off = (off + b + 255) & ~(size_t)255; return o; };
    float* nf   = (float*)(ws + alloc((size_t)N_ROWS * DIM * 4));
    float* ZA   = (float*)(ws + alloc((size_t)N_ROWS * NCLS * 4));   // logits, then Z ping buffer
    float* Y    = (float*)(ws + alloc((size_t)N_ROWS * NCLS * 4));
    float* pv   = (float*)(ws + alloc((size_t)JSPLIT * N_ROWS * KNB * 4));
    int*   pi_  = (int*)  (ws + alloc((size_t)JSPLIT * N_ROWS * KNB * 4));
    float* tv   = (float*)(ws + alloc((size_t)N_ROWS * KNB * 4));
    int*   ti_  = (int*)  (ws + alloc((size_t)N_ROWS * KNB * 4));
    float* deg  = (float*)(ws + alloc(N_ROWS * 4));
    int*   cnt  = (int*)  (ws + alloc(N_ROWS * 4));
    int*   rowptr = (int*)(ws + alloc((N_ROWS + 1) * 4));
    int*   cur  = (int*)  (ws + alloc(N_ROWS * 4));
    float* dis  = (float*)(ws + alloc(N_ROWS * 4));
    int*   cols = (int*)  (ws + alloc((size_t)2 * N_ROWS * KNB * 4));
    float* wts  = (float*)(ws + alloc((size_t)2 * N_ROWS * KNB * 4));
    if (off > ws_size) return;  // workspace too small; cannot proceed

    hipMemsetAsync(deg, 0, N_ROWS * 4, stream);
    hipMemsetAsync(cnt, 0, N_ROWS * 4, stream);

    rownorm_k<<<N_ROWS, 256, 0, stream>>>(feat, nf);

    dim3 gl(NTILES, (NCLS + 63) / 64);
    gemm_nt_k<<<gl, 256, 0, stream>>>(feat, cw, ZA, N_ROWS, NCLS);
    softmax_k<<<N_ROWS, 256, 0, stream>>>(ZA, Y);

    dim3 gs(NTILES, JSPLIT);
    simtopk_k<<<gs, 256, 0, stream>>>(nf, pv, pi_);
    topmerge_k<<<(N_ROWS + 255) / 256, 256, 0, stream>>>(pv, pi_, tv, ti_);

    edgecount_k<<<(N_ROWS * KNB + 255) / 256, 256, 0, stream>>>(tv, ti_, deg, cnt);
    scan_k<<<1, 1024, 0, stream>>>(cnt, rowptr, cur, deg, dis);
    fill_k<<<(N_ROWS * KNB + 255) / 256, 256, 0, stream>>>(tv, ti_, dis, cur, cols, wts);

    const float* zin = Y;
    for (int it = 0; it < NITER; ++it) {
        float* zout = (it & 1) ? out : ZA;     // it=19 (odd) lands on d_out
        spmv_k<<<N_ROWS, 256, 0, stream>>>(rowptr, cols, wts, zin, Y, zout);
        zin = zout;
    }
}

// Round 3
// 4469.151 us; speedup vs baseline: 1.1344x; 1.1344x over previous
//
#include <hip/hip_runtime.h>

#define N_ROWS 10000
#define DIM    768
#define NCLS   1000
#define KNB    10
#define NITER  20
#define EPSV   1e-8f
#define JSPLIT 16
#define NRT    79      // row tiles of 128 (ceil(10000/128))
#define NJT    79      // col tiles of 128
#define NT64   157     // ceil(10000/64) for classifier GEMM
#define MAXE   2048

typedef __attribute__((ext_vector_type(8))) short s8b;             // 8 bf16 (4 VGPR) MFMA frag
typedef __attribute__((ext_vector_type(4))) float f4;              // MFMA acc
typedef __attribute__((ext_vector_type(8))) unsigned short us8;
typedef __attribute__((ext_vector_type(4))) unsigned short us4;

__device__ __forceinline__ unsigned short f2bf(float x) {
    unsigned u = __float_as_uint(x);
    unsigned r = u + 0x7FFFu + ((u >> 16) & 1u);   // RN-even
    return (unsigned short)(r >> 16);
}
__device__ __forceinline__ float bf2f(unsigned short b) {
    return __uint_as_float(((unsigned)b) << 16);
}

// ---------------- row normalize -> bf16 hi/lo split ----------------
__global__ __launch_bounds__(192) void rownorm2_k(const float* __restrict__ feat,
                                                  unsigned short* __restrict__ nfh,
                                                  unsigned short* __restrict__ nfl) {
    int row = blockIdx.x;
    int t = threadIdx.x;                     // 192 threads, one float4 each
    const float4* src = (const float4*)(feat + (size_t)row * DIM);
    float4 v = src[t];
    float ss = v.x*v.x + v.y*v.y + v.z*v.z + v.w*v.w;
#pragma unroll
    for (int m = 1; m < 64; m <<= 1) ss += __shfl_xor(ss, m, 64);
    __shared__ float red[3];
    if ((t & 63) == 0) red[t >> 6] = ss;
    __syncthreads();
    float inv = 1.0f / (sqrtf(red[0] + red[1] + red[2]) + EPSV);
    float xs[4] = {v.x*inv, v.y*inv, v.z*inv, v.w*inv};
    us4 h, l;
#pragma unroll
    for (int j = 0; j < 4; ++j) {
        unsigned short hb = f2bf(xs[j]);
        h[j] = hb;
        l[j] = f2bf(xs[j] - bf2f(hb));
    }
    *(us4*)(nfh + (size_t)row * DIM + t*4) = h;
    *(us4*)(nfl + (size_t)row * DIM + t*4) = l;
}

// ---------------- fused sims (bf16x4 MFMA) + per-row top-10 partial ----------------
__global__ __launch_bounds__(256) void simtopk_k(const unsigned short* __restrict__ nfh,
                                                 const unsigned short* __restrict__ nfl,
                                                 float* __restrict__ pv,
                                                 int* __restrict__ pi_) {
    // staging: [row][k] with padded stride 40 halfwords (80B -> mild conflicts only)
    __shared__ unsigned short Ah[128*40], Al[128*40], Bh[128*40], Bl[128*40]; // 40 KiB
    __shared__ float dbuf[128*32];                                            // 16 KiB dump quarter

    int tid = threadIdx.x;
    int l = tid & 63, wid = tid >> 6;
    int wr = wid >> 1, wc = wid & 1;          // wave 2x2 grid, each 64x64
    int g = l >> 4, c = l & 15;               // MFMA lane decomposition

    // XCD-grouped swizzle: same-bi blocks land on 2 XCDs for A-panel L2 reuse
    int id = blockIdx.x;
    int pos = id >> 3, x8 = id & 7;
    int bi = pos % NRT;
    int js = x8 + 8 * (pos / NRT);
    int m0 = bi * 128;

    // persistent per-thread top-10 (2 threads per row)
    float lv[10]; int li[10];
#pragma unroll
    for (int s = 0; s < 10; ++s) { lv[s] = -1e30f; li[s] = 0x7fffffff; }
    int srow = tid >> 1;          // scan/stage row 0..127
    int chalf = tid & 1;
    int grow = m0 + srow;

    int skh = tid & 1;            // staging k-half
    const int agr = m0 + srow;
    bool aval = agr < N_ROWS;
    size_t abase = (size_t)agr * DIM + skh * 16;
    int lbase = srow * 40 + skh * 16;

    for (int jt = js; jt < NJT; jt += JSPLIT) {
        int n0 = jt * 128;
        f4 acc[4][4];
#pragma unroll
        for (int i = 0; i < 4; ++i)
#pragma unroll
            for (int j = 0; j < 4; ++j) acc[i][j] = (f4)0.0f;

        int bgr = n0 + srow;
        bool bval = bgr < N_ROWS;
        size_t bbase = (size_t)bgr * DIM + skh * 16;

        for (int ch = 0; ch < DIM / 32; ++ch) {
            size_t ao = abase + ch * 32;
            size_t bo = bbase + ch * 32;
            us8 a0h = aval ? *(const us8*)(nfh + ao)     : (us8)0;
            us8 a1h = aval ? *(const us8*)(nfh + ao + 8) : (us8)0;
            us8 a0l = aval ? *(const us8*)(nfl + ao)     : (us8)0;
            us8 a1l = aval ? *(const us8*)(nfl + ao + 8) : (us8)0;
            us8 b0h = bval ? *(const us8*)(nfh + bo)     : (us8)0;
            us8 b1h = bval ? *(const us8*)(nfh + bo + 8) : (us8)0;
            us8 b0l = bval ? *(const us8*)(nfl + bo)     : (us8)0;
            us8 b1l = bval ? *(const us8*)(nfl + bo + 8) : (us8)0;
            __syncthreads();     // prior iter's frag reads complete
            *(us8*)(Ah + lbase)     = a0h;  *(us8*)(Ah + lbase + 8) = a1h;
            *(us8*)(Al + lbase)     = a0l;  *(us8*)(Al + lbase + 8) = a1l;
            *(us8*)(Bh + lbase)     = b0h;  *(us8*)(Bh + lbase + 8) = b1h;
            *(us8*)(Bl + lbase)     = b0l;  *(us8*)(Bl + lbase + 8) = b1l;
            __syncthreads();

            s8b ah[4], al_[4];
#pragma unroll
            for (int rf = 0; rf < 4; ++rf) {
                int ro = (wr*64 + rf*16 + c) * 40 + g*8;
                ah[rf]  = *(const s8b*)(Ah + ro);
                al_[rf] = *(const s8b*)(Al + ro);
            }
#pragma unroll
            for (int cf = 0; cf < 4; ++cf) {
                int co = (wc*64 + cf*16 + c) * 40 + g*8;
                s8b bh = *(const s8b*)(Bh + co);
                s8b bl = *(const s8b*)(Bl + co);
#pragma unroll
                for (int rf = 0; rf < 4; ++rf) {
                    acc[rf][cf] = __builtin_amdgcn_mfma_f32_16x16x32_bf16(ah[rf],  bh, acc[rf][cf], 0, 0, 0);
                    acc[rf][cf] = __builtin_amdgcn_mfma_f32_16x16x32_bf16(al_[rf], bh, acc[rf][cf], 0, 0, 0);
                    acc[rf][cf] = __builtin_amdgcn_mfma_f32_16x16x32_bf16(ah[rf],  bl, acc[rf][cf], 0, 0, 0);
                    acc[rf][cf] = __builtin_amdgcn_mfma_f32_16x16x32_bf16(al_[rf], bl, acc[rf][cf], 0, 0, 0);
                }
            }
        }

        // epilogue: dump 32-col quarters to LDS, scan top-10
#pragma unroll 1
        for (int q = 0; q < 4; ++q) {
            __syncthreads();
            if (wc == (q >> 1)) {
                int cfb = (q & 1) * 2;
#pragma unroll
                for (int rf = 0; rf < 4; ++rf)
#pragma unroll
                    for (int c2 = 0; c2 < 2; ++c2) {
                        int cf = cfb + c2;
                        f4 a = acc[rf][cf];
                        int c5 = c2*16 + c;
#pragma unroll
                        for (int r = 0; r < 4; ++r) {
                            int rr = wr*64 + rf*16 + g*4 + r;
                            dbuf[rr*32 + (c5 ^ ((g & 1) << 4))] = a[r];
                        }
                    }
            }
            __syncthreads();
#pragma unroll
            for (int s = 0; s < 16; ++s) {
                int cc = (s + srow) & 15;
                int c5 = chalf*16 + cc;
                float val = dbuf[srow*32 + (c5 ^ (((srow >> 2) & 1) << 4))];
                int gcol = n0 + q*32 + c5;
                if (gcol < N_ROWS && gcol != grow && val > lv[9]) {
                    lv[9] = val; li[9] = gcol;
#pragma unroll
                    for (int u = 9; u > 0; --u) {
                        if (lv[u] > lv[u-1]) {
                            float t2 = lv[u]; lv[u] = lv[u-1]; lv[u-1] = t2;
                            int   t3 = li[u]; li[u] = li[u-1]; li[u-1] = t3;
                        }
                    }
                }
            }
        }
    }

    // merge the thread pair sharing each row; write partial top-10 for this split
#pragma unroll 1
    for (int sel = 0; sel < KNB; ++sel) {
        float bvv = lv[0]; int bii = li[0];
        float ov = __shfl_xor(bvv, 1, 2);
        int   oi = __shfl_xor(bii, 1, 2);
        bool other = (ov > bvv) || (ov == bvv && oi < bii);
        float wv = other ? ov : bvv;
        int   wi = other ? oi : bii;
        if (!other) {   // I won: pop my head
#pragma unroll
            for (int s = 0; s < 9; ++s) { lv[s] = lv[s+1]; li[s] = li[s+1]; }
            lv[9] = -1e30f; li[9] = 0x7fffffff;
        }
        if (chalf == 0 && grow < N_ROWS) {
            size_t o = ((size_t)js * N_ROWS + grow) * KNB + sel;
            pv[o] = wv; pi_[o] = wi;
        }
    }
}

// ---------------- generic C = A * B^T (64x64 tiles, 4x4/thread, fp32) ----------------
__global__ __launch_bounds__(256) void gemm_nt_k(const float* __restrict__ A,
                                                 const float* __restrict__ B,
                                                 float* __restrict__ Cout,
                                                 int M, int Nc) {
    __shared__ __align__(16) float As[16][64];
    __shared__ __align__(16) float Bs[16][64];
    int tid = threadIdx.x;
    int tx = tid & 15, ty = tid >> 4;
    int m0 = blockIdx.x * 64, n0 = blockIdx.y * 64;
    int lr = tid >> 2;
    int lk = (tid & 3) << 2;
    float acc[4][4];
#pragma unroll
    for (int i = 0; i < 4; ++i)
#pragma unroll
        for (int j = 0; j < 4; ++j) acc[i][j] = 0.f;

    int ar = m0 + lr, br = n0 + lr;
    bool aval = ar < M, bval = br < Nc;
    const float* arow = A + (size_t)ar * DIM + lk;
    const float* brow = B + (size_t)br * DIM + lk;
    float4 pa = aval ? *(const float4*)(arow) : make_float4(0,0,0,0);
    float4 pb = bval ? *(const float4*)(brow) : make_float4(0,0,0,0);

    for (int ch = 0; ch < DIM / 16; ++ch) {
        __syncthreads();
        As[lk+0][lr] = pa.x; As[lk+1][lr] = pa.y; As[lk+2][lr] = pa.z; As[lk+3][lr] = pa.w;
        Bs[lk+0][lr] = pb.x; Bs[lk+1][lr] = pb.y; Bs[lk+2][lr] = pb.z; Bs[lk+3][lr] = pb.w;
        __syncthreads();
        if (ch + 1 < DIM / 16) {
            int k0 = (ch + 1) * 16;
            pa = aval ? *(const float4*)(arow + k0) : make_float4(0,0,0,0);
            pb = bval ? *(const float4*)(brow + k0) : make_float4(0,0,0,0);
        }
#pragma unroll
        for (int kk = 0; kk < 16; ++kk) {
            float4 a4 = *(const float4*)(&As[kk][ty << 2]);
            float4 b4 = *(const float4*)(&Bs[kk][tx << 2]);
            float av[4] = {a4.x, a4.y, a4.z, a4.w};
            float bv[4] = {b4.x, b4.y, b4.z, b4.w};
#pragma unroll
            for (int i = 0; i < 4; ++i)
#pragma unroll
                for (int j = 0; j < 4; ++j) acc[i][j] = fmaf(av[i], bv[j], acc[i][j]);
        }
    }
#pragma unroll
    for (int i = 0; i < 4; ++i) {
        int r = m0 + (ty << 2) + i;
        if (r < M) {
#pragma unroll
            for (int j = 0; j < 4; ++j) {
                int cidx = n0 + (tx << 2) + j;
                if (cidx < Nc) Cout[(size_t)r * Nc + cidx] = acc[i][j];
            }
        }
    }
}

// ---------------- row softmax (C=1000) ----------------
__global__ __launch_bounds__(256) void softmax_k(const float* __restrict__ logits,
                                                 float* __restrict__ Y) {
    int row = blockIdx.x;
    const float* src = logits + (size_t)row * NCLS;
    __shared__ float sl[NCLS];
    __shared__ float red[4];
    int t = threadIdx.x;
    float mx = -1e30f;
    for (int cc = t; cc < NCLS; cc += 256) { float x = src[cc]; sl[cc] = x; mx = fmaxf(mx, x); }
#pragma unroll
    for (int m = 1; m < 64; m <<= 1) mx = fmaxf(mx, __shfl_xor(mx, m, 64));
    if ((t & 63) == 0) red[t >> 6] = mx;
    __syncthreads();
    mx = fmaxf(fmaxf(red[0], red[1]), fmaxf(red[2], red[3]));
    float sum = 0.f;
    for (int cc = t; cc < NCLS; cc += 256) { float e = expf(sl[cc] - mx); sl[cc] = e; sum += e; }
#pragma unroll
    for (int m = 1; m < 64; m <<= 1) sum += __shfl_xor(sum, m, 64);
    __syncthreads();
    if ((t & 63) == 0) red[t >> 6] = sum;
    __syncthreads();
    float inv = 1.0f / (red[0] + red[1] + red[2] + red[3]);
    float* dst = Y + (size_t)row * NCLS;
    for (int cc = t; cc < NCLS; cc += 256) dst[cc] = sl[cc] * inv;
}

// ---------------- final merge of JSPLIT partial top-10 lists ----------------
__global__ void topmerge_k(float* __restrict__ pv, const int* __restrict__ pi_,
                           float* __restrict__ tv, int* __restrict__ ti_) {
    int row = blockIdx.x * blockDim.x + threadIdx.x;
    if (row >= N_ROWS) return;
    for (int sel = 0; sel < KNB; ++sel) {
        float best = -1e30f; long bslot = -1;
        for (int js = 0; js < JSPLIT; ++js) {
            size_t base = ((size_t)js * N_ROWS + row) * KNB;
            for (int k = 0; k < KNB; ++k) {
                float v = pv[base + k];
                if (v > best) { best = v; bslot = (long)(base + k); }
            }
        }
        tv[(size_t)row * KNB + sel] = best;
        ti_[(size_t)row * KNB + sel] = pi_[bslot];
        pv[bslot] = -1e30f;
    }
}

// ---------------- graph build ----------------
__global__ void edgecount_k(const float* __restrict__ tv, const int* __restrict__ ti_,
                            float* __restrict__ deg, int* __restrict__ cnt) {
    int e = blockIdx.x * blockDim.x + threadIdx.x;
    if (e >= N_ROWS * KNB) return;
    int i = e / KNB;
    int j = ti_[e];
    float v = fmaxf(tv[e], 0.f);
    float w = 0.5f * v * v * v;
    atomicAdd(&deg[i], w);
    atomicAdd(&deg[j], w);
    atomicAdd(&cnt[i], 1);
    atomicAdd(&cnt[j], 1);
}

__global__ __launch_bounds__(1024) void scan_k(const int* __restrict__ cnt,
                                               int* __restrict__ rowptr,
                                               int* __restrict__ cur,
                                               const float* __restrict__ deg,
                                               float* __restrict__ dis) {
    __shared__ int sb[1024];
    int t = threadIdx.x;
    int carry = 0;
    for (int base = 0; base < N_ROWS; base += 1024) {
        int idx = base + t;
        int x = (idx < N_ROWS) ? cnt[idx] : 0;
        sb[t] = x;
        __syncthreads();
        for (int offc = 1; offc < 1024; offc <<= 1) {
            int add = (t >= offc) ? sb[t - offc] : 0;
            __syncthreads();
            sb[t] += add;
            __syncthreads();
        }
        int incl = sb[t];
        int tot = sb[1023];
        if (idx < N_ROWS) {
            rowptr[idx + 1] = carry + incl;
            cur[idx] = carry + incl - x;
            if (idx == 0) rowptr[0] = 0;
            dis[idx] = 1.0f / (sqrtf(deg[idx] + EPSV));
        }
        __syncthreads();
        carry += tot;
    }
}

__global__ void fill_k(const float* __restrict__ tv, const int* __restrict__ ti_,
                       const float* __restrict__ dis, int* __restrict__ cur,
                       int* __restrict__ cols, float* __restrict__ wts) {
    int e = blockIdx.x * blockDim.x + threadIdx.x;
    if (e >= N_ROWS * KNB) return;
    int i = e / KNB;
    int j = ti_[e];
    float v = fmaxf(tv[e], 0.f);
    float w = 0.5f * v * v * v;
    float s = 0.99f * w * dis[i] * dis[j];   // ALPHA folded into edge weight
    int p1 = atomicAdd(&cur[i], 1); cols[p1] = j; wts[p1] = s;
    int p2 = atomicAdd(&cur[j], 1); cols[p2] = i; wts[p2] = s;
}

// ---------------- sparse propagation step ----------------
__global__ __launch_bounds__(256) void spmv_k(const int* __restrict__ rowptr,
                                              const int* __restrict__ cols,
                                              const float* __restrict__ wts,
                                              const float* __restrict__ Zin,
                                              const float* __restrict__ Y,
                                              float* __restrict__ Zout) {
    int i = blockIdx.x;
    int b = rowptr[i], e = rowptr[i + 1];
    int nnz = e - b;
    __shared__ int   cs[MAXE];
    __shared__ float wsh[MAXE];
    int nl = min(nnz, MAXE);
    for (int t = threadIdx.x; t < nl; t += 256) { cs[t] = cols[b + t]; wsh[t] = wts[b + t]; }
    __syncthreads();
    const float beta = (float)(1.0 - 0.99);
    for (int cc = threadIdx.x; cc < NCLS; cc += 256) {
        float acc = beta * Y[(size_t)i * NCLS + cc];
        for (int k = 0; k < nl; ++k) acc += wsh[k] * Zin[(size_t)cs[k] * NCLS + cc];
        for (int k = MAXE; k < nnz; ++k) acc += wts[b + k] * Zin[(size_t)cols[b + k] * NCLS + cc];
        Zout[(size_t)i * NCLS + cc] = acc;
    }
}

extern "C" void kernel_launch(void* const* d_in, const int* in_sizes, int n_in,
                              void* d_out, int out_size, void* d_ws, size_t ws_size,
                              hipStream_t stream) {
    const float* feat = (const float*)d_in[0];
    const float* cw   = (const float*)d_in[1];
    float* out = (float*)d_out;
    char* ws = (char*)d_ws;
    size_t off = 0;
    auto alloc = [&](size_t b) { size_t o = off; off = (off + b + 255) & ~(size_t)255; return o; };
    unsigned short* nfh = (unsigned short*)(ws + alloc((size_t)N_ROWS * DIM * 2));
    unsigned short* nfl = (unsigned short*)(ws + alloc((size_t)N_ROWS * DIM * 2));
    float* ZA   = (float*)(ws + alloc((size_t)N_ROWS * NCLS * 4));   // logits, then Z ping buffer
    float* Y    = (float*)(ws + alloc((size_t)N_ROWS * NCLS * 4));
    float* pv   = (float*)(ws + alloc((size_t)JSPLIT * N_ROWS * KNB * 4));
    int*   pi_  = (int*)  (ws + alloc((size_t)JSPLIT * N_ROWS * KNB * 4));
    float* tv   = (float*)(ws + alloc((size_t)N_ROWS * KNB * 4));
    int*   ti_  = (int*)  (ws + alloc((size_t)N_ROWS * KNB * 4));
    float* deg  = (float*)(ws + alloc(N_ROWS * 4));
    int*   cnt  = (int*)  (ws + alloc(N_ROWS * 4));
    int*   rowptr = (int*)(ws + alloc((N_ROWS + 1) * 4));
    int*   cur  = (int*)  (ws + alloc(N_ROWS * 4));
    float* dis  = (float*)(ws + alloc(N_ROWS * 4));
    int*   cols = (int*)  (ws + alloc((size_t)2 * N_ROWS * KNB * 4));
    float* wts  = (float*)(ws + alloc((size_t)2 * N_ROWS * KNB * 4));
    if (off > ws_size) return;

    hipMemsetAsync(deg, 0, N_ROWS * 4, stream);
    hipMemsetAsync(cnt, 0, N_ROWS * 4, stream);

    rownorm2_k<<<N_ROWS, 192, 0, stream>>>(feat, nfh, nfl);

    dim3 gl(NT64, (NCLS + 63) / 64);
    gemm_nt_k<<<gl, 256, 0, stream>>>(feat, cw, ZA, N_ROWS, NCLS);
    softmax_k<<<N_ROWS, 256, 0, stream>>>(ZA, Y);

    simtopk_k<<<NRT * JSPLIT, 256, 0, stream>>>(nfh, nfl, pv, pi_);
    topmerge_k<<<(N_ROWS + 255) / 256, 256, 0, stream>>>(pv, pi_, tv, ti_);

    edgecount_k<<<(N_ROWS * KNB + 255) / 256, 256, 0, stream>>>(tv, ti_, deg, cnt);
    scan_k<<<1, 1024, 0, stream>>>(cnt, rowptr, cur, deg, dis);
    fill_k<<<(N_ROWS * KNB + 255) / 256, 256, 0, stream>>>(tv, ti_, dis, cur, cols, wts);

    const float* zin = Y;
    for (int it = 0; it < NITER; ++it) {
        float* zout = (it & 1) ? out : ZA;     // it=19 (odd) lands on d_out
        spmv_k<<<N_ROWS, 256, 0, stream>>>(rowptr, cols, wts, zin, Y, zout);
        zin = zout;
    }
}

// Round 4
// 2876.743 us; speedup vs baseline: 1.7624x; 1.5535x over previous
//
#include <hip/hip_runtime.h>

#define N_ROWS 10000
#define DIM    768
#define NCLS   1000
#define KNB    10
#define NITER  20
#define EPSV   1e-8f
#define JSPLIT 16
#define NRT    79      // row tiles of 128 (ceil(10000/128))
#define NJT    79      // col tiles of 128
#define NT64   157     // ceil(10000/64) for classifier GEMM
#define MAXE   2048

typedef __attribute__((ext_vector_type(8))) short s8b;             // 8 bf16 (4 VGPR) MFMA frag
typedef __attribute__((ext_vector_type(4))) float f4;              // MFMA acc
typedef __attribute__((ext_vector_type(8))) unsigned short us8;
typedef __attribute__((ext_vector_type(4))) unsigned short us4;

__device__ __forceinline__ unsigned short f2bf(float x) {
    unsigned u = __float_as_uint(x);
    unsigned r = u + 0x7FFFu + ((u >> 16) & 1u);   // RN-even
    return (unsigned short)(r >> 16);
}
__device__ __forceinline__ float bf2f(unsigned short b) {
    return __uint_as_float(((unsigned)b) << 16);
}

// ---------------- row normalize -> bf16 hi/lo split ----------------
__global__ __launch_bounds__(192) void rownorm2_k(const float* __restrict__ feat,
                                                  unsigned short* __restrict__ nfh,
                                                  unsigned short* __restrict__ nfl) {
    int row = blockIdx.x;
    int t = threadIdx.x;                     // 192 threads, one float4 each
    const float4* src = (const float4*)(feat + (size_t)row * DIM);
    float4 v = src[t];
    float ss = v.x*v.x + v.y*v.y + v.z*v.z + v.w*v.w;
#pragma unroll
    for (int m = 1; m < 64; m <<= 1) ss += __shfl_xor(ss, m, 64);
    __shared__ float red[3];
    if ((t & 63) == 0) red[t >> 6] = ss;
    __syncthreads();
    float inv = 1.0f / (sqrtf(red[0] + red[1] + red[2]) + EPSV);
    float xs[4] = {v.x*inv, v.y*inv, v.z*inv, v.w*inv};
    us4 h, l;
#pragma unroll
    for (int j = 0; j < 4; ++j) {
        unsigned short hb = f2bf(xs[j]);
        h[j] = hb;
        l[j] = f2bf(xs[j] - bf2f(hb));
    }
    *(us4*)(nfh + (size_t)row * DIM + t*4) = h;
    *(us4*)(nfl + (size_t)row * DIM + t*4) = l;
}

// ---------------- fused sims (bf16x4 MFMA) + per-row top-10 partial ----------------
__global__ __launch_bounds__(256) void simtopk_k(const unsigned short* __restrict__ nfh,
                                                 const unsigned short* __restrict__ nfl,
                                                 float* __restrict__ pv,
                                                 int* __restrict__ pi_) {
    // staging: [row][k] with padded stride 40 halfwords (80B -> mild conflicts only)
    __shared__ unsigned short Ah[128*40], Al[128*40], Bh[128*40], Bl[128*40]; // 40 KiB
    __shared__ float dbuf[128*32];                                            // 16 KiB dump quarter

    int tid = threadIdx.x;
    int l = tid & 63, wid = tid >> 6;
    int wr = wid >> 1, wc = wid & 1;          // wave 2x2 grid, each 64x64
    int g = l >> 4, c = l & 15;               // MFMA lane decomposition

    // XCD-grouped swizzle: same-bi blocks land on 2 XCDs for A-panel L2 reuse
    int id = blockIdx.x;
    int pos = id >> 3, x8 = id & 7;
    int bi = pos % NRT;
    int js = x8 + 8 * (pos / NRT);
    int m0 = bi * 128;

    // persistent per-thread top-10 (2 threads per row)
    float lv[10]; int li[10];
#pragma unroll
    for (int s = 0; s < 10; ++s) { lv[s] = -1e30f; li[s] = 0x7fffffff; }
    int srow = tid >> 1;          // scan/stage row 0..127
    int chalf = tid & 1;
    int grow = m0 + srow;

    int skh = tid & 1;            // staging k-half
    const int agr = m0 + srow;
    bool aval = agr < N_ROWS;
    size_t abase = (size_t)agr * DIM + skh * 16;
    int lbase = srow * 40 + skh * 16;

    for (int jt = js; jt < NJT; jt += JSPLIT) {
        int n0 = jt * 128;
        f4 acc[4][4];
#pragma unroll
        for (int i = 0; i < 4; ++i)
#pragma unroll
            for (int j = 0; j < 4; ++j) acc[i][j] = (f4)0.0f;

        int bgr = n0 + srow;
        bool bval = bgr < N_ROWS;
        size_t bbase = (size_t)bgr * DIM + skh * 16;

        for (int ch = 0; ch < DIM / 32; ++ch) {
            size_t ao = abase + ch * 32;
            size_t bo = bbase + ch * 32;
            us8 a0h = aval ? *(const us8*)(nfh + ao)     : (us8)0;
            us8 a1h = aval ? *(const us8*)(nfh + ao + 8) : (us8)0;
            us8 a0l = aval ? *(const us8*)(nfl + ao)     : (us8)0;
            us8 a1l = aval ? *(const us8*)(nfl + ao + 8) : (us8)0;
            us8 b0h = bval ? *(const us8*)(nfh + bo)     : (us8)0;
            us8 b1h = bval ? *(const us8*)(nfh + bo + 8) : (us8)0;
            us8 b0l = bval ? *(const us8*)(nfl + bo)     : (us8)0;
            us8 b1l = bval ? *(const us8*)(nfl + bo + 8) : (us8)0;
            __syncthreads();     // prior iter's frag reads complete
            *(us8*)(Ah + lbase)     = a0h;  *(us8*)(Ah + lbase + 8) = a1h;
            *(us8*)(Al + lbase)     = a0l;  *(us8*)(Al + lbase + 8) = a1l;
            *(us8*)(Bh + lbase)     = b0h;  *(us8*)(Bh + lbase + 8) = b1h;
            *(us8*)(Bl + lbase)     = b0l;  *(us8*)(Bl + lbase + 8) = b1l;
            __syncthreads();

            s8b ah[4], al_[4];
#pragma unroll
            for (int rf = 0; rf < 4; ++rf) {
                int ro = (wr*64 + rf*16 + c) * 40 + g*8;
                ah[rf]  = *(const s8b*)(Ah + ro);
                al_[rf] = *(const s8b*)(Al + ro);
            }
#pragma unroll
            for (int cf = 0; cf < 4; ++cf) {
                int co = (wc*64 + cf*16 + c) * 40 + g*8;
                s8b bh = *(const s8b*)(Bh + co);
                s8b bl = *(const s8b*)(Bl + co);
#pragma unroll
                for (int rf = 0; rf < 4; ++rf) {
                    acc[rf][cf] = __builtin_amdgcn_mfma_f32_16x16x32_bf16(ah[rf],  bh, acc[rf][cf], 0, 0, 0);
                    acc[rf][cf] = __builtin_amdgcn_mfma_f32_16x16x32_bf16(al_[rf], bh, acc[rf][cf], 0, 0, 0);
                    acc[rf][cf] = __builtin_amdgcn_mfma_f32_16x16x32_bf16(ah[rf],  bl, acc[rf][cf], 0, 0, 0);
                    acc[rf][cf] = __builtin_amdgcn_mfma_f32_16x16x32_bf16(al_[rf], bl, acc[rf][cf], 0, 0, 0);
                }
            }
        }

        // epilogue: dump 32-col quarters to LDS, scan top-10.
        // FULLY UNROLLED over q: rule #20 — a runtime q made acc[rf][cf]
        // dynamically indexed, sending the whole acc tile to scratch
        // (8.9 GB HBM WRITE_SIZE in r3 profile). Static q keeps acc in VGPRs.
#pragma unroll
        for (int q = 0; q < 4; ++q) {
            __syncthreads();
            if (wc == (q >> 1)) {
                int cfb = (q & 1) * 2;
#pragma unroll
                for (int rf = 0; rf < 4; ++rf)
#pragma unroll
                    for (int c2 = 0; c2 < 2; ++c2) {
                        int cf = cfb + c2;
                        f4 a = acc[rf][cf];
                        int c5 = c2*16 + c;
#pragma unroll
                        for (int r = 0; r < 4; ++r) {
                            int rr = wr*64 + rf*16 + g*4 + r;
                            dbuf[rr*32 + (c5 ^ ((g & 1) << 4))] = a[r];
                        }
                    }
            }
            __syncthreads();
#pragma unroll
            for (int s = 0; s < 16; ++s) {
                int cc = (s + srow) & 15;
                int c5 = chalf*16 + cc;
                float val = dbuf[srow*32 + (c5 ^ (((srow >> 2) & 1) << 4))];
                int gcol = n0 + q*32 + c5;
                if (gcol < N_ROWS && gcol != grow && val > lv[9]) {
                    lv[9] = val; li[9] = gcol;
#pragma unroll
                    for (int u = 9; u > 0; --u) {
                        if (lv[u] > lv[u-1]) {
                            float t2 = lv[u]; lv[u] = lv[u-1]; lv[u-1] = t2;
                            int   t3 = li[u]; li[u] = li[u-1]; li[u-1] = t3;
                        }
                    }
                }
            }
        }
    }

    // merge the thread pair sharing each row; write partial top-10 for this split
#pragma unroll 1
    for (int sel = 0; sel < KNB; ++sel) {
        float bvv = lv[0]; int bii = li[0];
        float ov = __shfl_xor(bvv, 1, 2);
        int   oi = __shfl_xor(bii, 1, 2);
        bool other = (ov > bvv) || (ov == bvv && oi < bii);
        float wv = other ? ov : bvv;
        int   wi = other ? oi : bii;
        if (!other) {   // I won: pop my head
#pragma unroll
        for (int s = 0; s < 9; ++s) { lv[s] = lv[s+1]; li[s] = li[s+1]; }
            lv[9] = -1e30f; li[9] = 0x7fffffff;
        }
        if (chalf == 0 && grow < N_ROWS) {
            size_t o = ((size_t)js * N_ROWS + grow) * KNB + sel;
            pv[o] = wv; pi_[o] = wi;
        }
    }
}

// ---------------- generic C = A * B^T (64x64 tiles, 4x4/thread, fp32) ----------------
__global__ __launch_bounds__(256) void gemm_nt_k(const float* __restrict__ A,
                                                 const float* __restrict__ B,
                                                 float* __restrict__ Cout,
                                                 int M, int Nc) {
    __shared__ __align__(16) float As[16][64];
    __shared__ __align__(16) float Bs[16][64];
    int tid = threadIdx.x;
    int tx = tid & 15, ty = tid >> 4;
    int m0 = blockIdx.x * 64, n0 = blockIdx.y * 64;
    int lr = tid >> 2;
    int lk = (tid & 3) << 2;
    float acc[4][4];
#pragma unroll
    for (int i = 0; i < 4; ++i)
#pragma unroll
        for (int j = 0; j < 4; ++j) acc[i][j] = 0.f;

    int ar = m0 + lr, br = n0 + lr;
    bool aval = ar < M, bval = br < Nc;
    const float* arow = A + (size_t)ar * DIM + lk;
    const float* brow = B + (size_t)br * DIM + lk;
    float4 pa = aval ? *(const float4*)(arow) : make_float4(0,0,0,0);
    float4 pb = bval ? *(const float4*)(brow) : make_float4(0,0,0,0);

    for (int ch = 0; ch < DIM / 16; ++ch) {
        __syncthreads();
        As[lk+0][lr] = pa.x; As[lk+1][lr] = pa.y; As[lk+2][lr] = pa.z; As[lk+3][lr] = pa.w;
        Bs[lk+0][lr] = pb.x; Bs[lk+1][lr] = pb.y; Bs[lk+2][lr] = pb.z; Bs[lk+3][lr] = pb.w;
        __syncthreads();
        if (ch + 1 < DIM / 16) {
            int k0 = (ch + 1) * 16;
            pa = aval ? *(const float4*)(arow + k0) : make_float4(0,0,0,0);
            pb = bval ? *(const float4*)(brow + k0) : make_float4(0,0,0,0);
        }
#pragma unroll
        for (int kk = 0; kk < 16; ++kk) {
            float4 a4 = *(const float4*)(&As[kk][ty << 2]);
            float4 b4 = *(const float4*)(&Bs[kk][tx << 2]);
            float av[4] = {a4.x, a4.y, a4.z, a4.w};
            float bv[4] = {b4.x, b4.y, b4.z, b4.w};
#pragma unroll
            for (int i = 0; i < 4; ++i)
#pragma unroll
                for (int j = 0; j < 4; ++j) acc[i][j] = fmaf(av[i], bv[j], acc[i][j]);
        }
    }
#pragma unroll
    for (int i = 0; i < 4; ++i) {
        int r = m0 + (ty << 2) + i;
        if (r < M) {
#pragma unroll
            for (int j = 0; j < 4; ++j) {
                int cidx = n0 + (tx << 2) + j;
                if (cidx < Nc) Cout[(size_t)r * Nc + cidx] = acc[i][j];
            }
        }
    }
}

// ---------------- row softmax (C=1000) ----------------
__global__ __launch_bounds__(256) void softmax_k(const float* __restrict__ logits,
                                                 float* __restrict__ Y) {
    int row = blockIdx.x;
    const float* src = logits + (size_t)row * NCLS;
    __shared__ float sl[NCLS];
    __shared__ float red[4];
    int t = threadIdx.x;
    float mx = -1e30f;
    for (int cc = t; cc < NCLS; cc += 256) { float x = src[cc]; sl[cc] = x; mx = fmaxf(mx, x); }
#pragma unroll
    for (int m = 1; m < 64; m <<= 1) mx = fmaxf(mx, __shfl_xor(mx, m, 64));
    if ((t & 63) == 0) red[t >> 6] = mx;
    __syncthreads();
    mx = fmaxf(fmaxf(red[0], red[1]), fmaxf(red[2], red[3]));
    float sum = 0.f;
    for (int cc = t; cc < NCLS; cc += 256) { float e = expf(sl[cc] - mx); sl[cc] = e; sum += e; }
#pragma unroll
    for (int m = 1; m < 64; m <<= 1) sum += __shfl_xor(sum, m, 64);
    __syncthreads();
    if ((t & 63) == 0) red[t >> 6] = sum;
    __syncthreads();
    float inv = 1.0f / (red[0] + red[1] + red[2] + red[3]);
    float* dst = Y + (size_t)row * NCLS;
    for (int cc = t; cc < NCLS; cc += 256) dst[cc] = sl[cc] * inv;
}

// ---------------- final merge of JSPLIT partial top-10 lists ----------------
__global__ void topmerge_k(float* __restrict__ pv, const int* __restrict__ pi_,
                           float* __restrict__ tv, int* __restrict__ ti_) {
    int row = blockIdx.x * blockDim.x + threadIdx.x;
    if (row >= N_ROWS) return;
    for (int sel = 0; sel < KNB; ++sel) {
        float best = -1e30f; long bslot = -1;
        for (int js = 0; js < JSPLIT; ++js) {
            size_t base = ((size_t)js * N_ROWS + row) * KNB;
            for (int k = 0; k < KNB; ++k) {
                float v = pv[base + k];
                if (v > best) { best = v; bslot = (long)(base + k); }
            }
        }
        tv[(size_t)row * KNB + sel] = best;
        ti_[(size_t)row * KNB + sel] = pi_[bslot];
        pv[bslot] = -1e30f;
    }
}

// ---------------- graph build ----------------
__global__ void edgecount_k(const float* __restrict__ tv, const int* __restrict__ ti_,
                            float* __restrict__ deg, int* __restrict__ cnt) {
    int e = blockIdx.x * blockDim.x + threadIdx.x;
    if (e >= N_ROWS * KNB) return;
    int i = e / KNB;
    int j = ti_[e];
    float v = fmaxf(tv[e], 0.f);
    float w = 0.5f * v * v * v;
    atomicAdd(&deg[i], w);
    atomicAdd(&deg[j], w);
    atomicAdd(&cnt[i], 1);
    atomicAdd(&cnt[j], 1);
}

__global__ __launch_bounds__(1024) void scan_k(const int* __restrict__ cnt,
                                               int* __restrict__ rowptr,
                                               int* __restrict__ cur,
                                               const float* __restrict__ deg,
                                               float* __restrict__ dis) {
    __shared__ int sb[1024];
    int t = threadIdx.x;
    int carry = 0;
    for (int base = 0; base < N_ROWS; base += 1024) {
        int idx = base + t;
        int x = (idx < N_ROWS) ? cnt[idx] : 0;
        sb[t] = x;
        __syncthreads();
        for (int offc = 1; offc < 1024; offc <<= 1) {
            int add = (t >= offc) ? sb[t - offc] : 0;
            __syncthreads();
            sb[t] += add;
            __syncthreads();
        }
        int incl = sb[t];
        int tot = sb[1023];
        if (idx < N_ROWS) {
            rowptr[idx + 1] = carry + incl;
            cur[idx] = carry + incl - x;
            if (idx == 0) rowptr[0] = 0;
            dis[idx] = 1.0f / (sqrtf(deg[idx] + EPSV));
        }
        __syncthreads();
        carry += tot;
    }
}

__global__ void fill_k(const float* __restrict__ tv, const int* __restrict__ ti_,
                       const float* __restrict__ dis, int* __restrict__ cur,
                       int* __restrict__ cols, float* __restrict__ wts) {
    int e = blockIdx.x * blockDim.x + threadIdx.x;
    if (e >= N_ROWS * KNB) return;
    int i = e / KNB;
    int j = ti_[e];
    float v = fmaxf(tv[e], 0.f);
    float w = 0.5f * v * v * v;
    float s = 0.99f * w * dis[i] * dis[j];   // ALPHA folded into edge weight
    int p1 = atomicAdd(&cur[i], 1); cols[p1] = j; wts[p1] = s;
    int p2 = atomicAdd(&cur[j], 1); cols[p2] = i; wts[p2] = s;
}

// ---------------- sparse propagation step ----------------
__global__ __launch_bounds__(256) void spmv_k(const int* __restrict__ rowptr,
                                              const int* __restrict__ cols,
                                              const float* __restrict__ wts,
                                              const float* __restrict__ Zin,
                                              const float* __restrict__ Y,
                                              float* __restrict__ Zout) {
    int i = blockIdx.x;
    int b = rowptr[i], e = rowptr[i + 1];
    int nnz = e - b;
    __shared__ int   cs[MAXE];
    __shared__ float wsh[MAXE];
    int nl = min(nnz, MAXE);
    for (int t = threadIdx.x; t < nl; t += 256) { cs[t] = cols[b + t]; wsh[t] = wts[b + t]; }
    __syncthreads();
    const float beta = (float)(1.0 - 0.99);
    for (int cc = threadIdx.x; cc < NCLS; cc += 256) {
        float acc = beta * Y[(size_t)i * NCLS + cc];
        for (int k = 0; k < nl; ++k) acc += wsh[k] * Zin[(size_t)cs[k] * NCLS + cc];
        for (int k = MAXE; k < nnz; ++k) acc += wts[b + k] * Zin[(size_t)cols[b + k] * NCLS + cc];
        Zout[(size_t)i * NCLS + cc] = acc;
    }
}

extern "C" void kernel_launch(void* const* d_in, const int* in_sizes, int n_in,
                              void* d_out, int out_size, void* d_ws, size_t ws_size,
                              hipStream_t stream) {
    const float* feat = (const float*)d_in[0];
    const float* cw   = (const float*)d_in[1];
    float* out = (float*)d_out;
    char* ws = (char*)d_ws;
    size_t off = 0;
    auto alloc = [&](size_t b) { size_t o = off; off = (off + b + 255) & ~(size_t)255; return o; };
    unsigned short* nfh = (unsigned short*)(ws + alloc((size_t)N_ROWS * DIM * 2));
    unsigned short* nfl = (unsigned short*)(ws + alloc((size_t)N_ROWS * DIM * 2));
    float* ZA   = (float*)(ws + alloc((size_t)N_ROWS * NCLS * 4));   // logits, then Z ping buffer
    float* Y    = (float*)(ws + alloc((size_t)N_ROWS * NCLS * 4));
    float* pv   = (float*)(ws + alloc((size_t)JSPLIT * N_ROWS * KNB * 4));
    int*   pi_  = (int*)  (ws + alloc((size_t)JSPLIT * N_ROWS * KNB * 4));
    float* tv   = (float*)(ws + alloc((size_t)N_ROWS * KNB * 4));
    int*   ti_  = (int*)  (ws + alloc((size_t)N_ROWS * KNB * 4));
    float* deg  = (float*)(ws + alloc(N_ROWS * 4));
    int*   cnt  = (int*)  (ws + alloc(N_ROWS * 4));
    int*   rowptr = (int*)(ws + alloc((N_ROWS + 1) * 4));
    int*   cur  = (int*)  (ws + alloc(N_ROWS * 4));
    float* dis  = (float*)(ws + alloc(N_ROWS * 4));
    int*   cols = (int*)  (ws + alloc((size_t)2 * N_ROWS * KNB * 4));
    float* wts  = (float*)(ws + alloc((size_t)2 * N_ROWS * KNB * 4));
    if (off > ws_size) return;

    hipMemsetAsync(deg, 0, N_ROWS * 4, stream);
    hipMemsetAsync(cnt, 0, N_ROWS * 4, stream);

    rownorm2_k<<<N_ROWS, 192, 0, stream>>>(feat, nfh, nfl);

    dim3 gl(NT64, (NCLS + 63) / 64);
    gemm_nt_k<<<gl, 256, 0, stream>>>(feat, cw, ZA, N_ROWS, NCLS);
    softmax_k<<<N_ROWS, 256, 0, stream>>>(ZA, Y);

    simtopk_k<<<NRT * JSPLIT, 256, 0, stream>>>(nfh, nfl, pv, pi_);
    topmerge_k<<<(N_ROWS + 255) / 256, 256, 0, stream>>>(pv, pi_, tv, ti_);

    edgecount_k<<<(N_ROWS * KNB + 255) / 256, 256, 0, stream>>>(tv, ti_, deg, cnt);
    scan_k<<<1, 1024, 0, stream>>>(cnt, rowptr, cur, deg, dis);
    fill_k<<<(N_ROWS * KNB + 255) / 256, 256, 0, stream>>>(tv, ti_, dis, cur, cols, wts);

    const float* zin = Y;
    for (int it = 0; it < NITER; ++it) {
        float* zout = (it & 1) ? out : ZA;     // it=19 (odd) lands on d_out
        spmv_k<<<N_ROWS, 256, 0, stream>>>(rowptr, cols, wts, zin, Y, zout);
        zin = zout;
    }
}

// Round 5
// 2672.762 us; speedup vs baseline: 1.8969x; 1.0763x over previous
//
#include <hip/hip_runtime.h>

#define N_ROWS 10000
#define DIM    768
#define NCLS   1000
#define KNB    10
#define NITER  20
#define EPSV   1e-8f
#define JSPLIT 16
#define NRT    79      // row tiles of 128
#define NJT    79      // col tiles of 128
#define NCT    8       // classifier col tiles of 128 (1000 -> 8)
#define MAXE   2048
#define STR    40      // LDS halfword stride per 32-k row slice

typedef __attribute__((ext_vector_type(8))) short s8b;             // MFMA bf16 frag
typedef __attribute__((ext_vector_type(4))) float f4;              // MFMA acc
typedef __attribute__((ext_vector_type(8))) unsigned short us8;
typedef __attribute__((ext_vector_type(4))) unsigned short us4;

__device__ __forceinline__ unsigned short f2bf(float x) {
    unsigned u = __float_as_uint(x);
    unsigned r = u + 0x7FFFu + ((u >> 16) & 1u);   // RN-even
    return (unsigned short)(r >> 16);
}
__device__ __forceinline__ float bf2f(unsigned short b) {
    return __uint_as_float(((unsigned)b) << 16);
}

// ---------------- row normalize -> bf16 hi/lo split + norm save ----------------
__global__ __launch_bounds__(192) void rownorm2_k(const float* __restrict__ feat,
                                                  unsigned short* __restrict__ nfh,
                                                  unsigned short* __restrict__ nfl,
                                                  float* __restrict__ rnorm) {
    int row = blockIdx.x;
    int t = threadIdx.x;
    const float4* src = (const float4*)(feat + (size_t)row * DIM);
    float4 v = src[t];
    float ss = v.x*v.x + v.y*v.y + v.z*v.z + v.w*v.w;
#pragma unroll
    for (int m = 1; m < 64; m <<= 1) ss += __shfl_xor(ss, m, 64);
    __shared__ float red[3];
    if ((t & 63) == 0) red[t >> 6] = ss;
    __syncthreads();
    float nrm = sqrtf(red[0] + red[1] + red[2]) + EPSV;
    float inv = 1.0f / nrm;
    if (t == 0) rnorm[row] = nrm;
    float xs[4] = {v.x*inv, v.y*inv, v.z*inv, v.w*inv};
    us4 h, l;
#pragma unroll
    for (int j = 0; j < 4; ++j) {
        unsigned short hb = f2bf(xs[j]);
        h[j] = hb;
        l[j] = f2bf(xs[j] - bf2f(hb));
    }
    *(us4*)(nfh + (size_t)row * DIM + t*4) = h;
    *(us4*)(nfl + (size_t)row * DIM + t*4) = l;
}

// ---------------- generic fp32 -> bf16 hi/lo split (for cw) ----------------
__global__ void split_k(const float* __restrict__ src,
                        unsigned short* __restrict__ h,
                        unsigned short* __restrict__ l, int n4) {
    int i = blockIdx.x * blockDim.x + threadIdx.x;
    if (i >= n4) return;
    float4 v = ((const float4*)src)[i];
    float xs[4] = {v.x, v.y, v.z, v.w};
    us4 hh, ll;
#pragma unroll
    for (int j = 0; j < 4; ++j) {
        unsigned short hb = f2bf(xs[j]);
        hh[j] = hb;
        ll[j] = f2bf(xs[j] - bf2f(hb));
    }
    ((us4*)h)[i] = hh; ((us4*)l)[i] = ll;
}

// ---------------- fused sims (bf16 3-term MFMA) + in-register top-10 ----------------
// Swapped operands: mfma(b_frag, a_frag) -> lane (c=l&15) holds row m0+w*32+rf*16+c,
// cols cf*16 + g*4 + r in regs. Top-10 stays in VGPRs; no dump buffer, no epilogue LDS.
__global__ __launch_bounds__(256, 2) void simtopk_k(const unsigned short* __restrict__ nfh,
                                                    const unsigned short* __restrict__ nfl,
                                                    float* __restrict__ pv,
                                                    int* __restrict__ pi_) {
    // [buf][plane: Ah,Al,Bh,Bl][128 rows * STR]  -> 2*4*5120*2B = 81920 B (2 blocks/CU)
    __shared__ __align__(16) unsigned short S[2][4][128 * STR];

    int tid = threadIdx.x;
    int l = tid & 63, w = tid >> 6;           // wave w covers rows w*32..w*32+31
    int g = l >> 4, c = l & 15;

    int id = blockIdx.x;
    int pos = id >> 3, x8 = id & 7;           // XCD-grouped swizzle
    int bi = pos % NRT;
    int js = x8 + 8 * (pos / NRT);
    int m0 = bi * 128;

    float lv[2][10]; int li[2][10];
#pragma unroll
    for (int rf = 0; rf < 2; ++rf)
#pragma unroll
        for (int s = 0; s < 10; ++s) { lv[rf][s] = -1e30f; li[rf][s] = 0x7fffffff; }

    int srow = tid >> 1, skh = tid & 1;
    int agr = m0 + srow;
    bool aval = agr < N_ROWS;
    size_t abase = (size_t)agr * DIM + skh * 16;
    int lbase = srow * STR + skh * 16;

    us8 rah0, rah1, ral0, ral1, rbh0, rbh1, rbl0, rbl1;
    // prologue: load regs for (jt=js, ch=0)
    {
        size_t ao = abase;
        rah0 = aval ? *(const us8*)(nfh + ao)     : (us8)0;
        rah1 = aval ? *(const us8*)(nfh + ao + 8) : (us8)0;
        ral0 = aval ? *(const us8*)(nfl + ao)     : (us8)0;
        ral1 = aval ? *(const us8*)(nfl + ao + 8) : (us8)0;
        int bgr = js * 128 + srow;
        bool bval = bgr < N_ROWS;
        size_t bo = (size_t)bgr * DIM + skh * 16;
        rbh0 = bval ? *(const us8*)(nfh + bo)     : (us8)0;
        rbh1 = bval ? *(const us8*)(nfh + bo + 8) : (us8)0;
        rbl0 = bval ? *(const us8*)(nfl + bo)     : (us8)0;
        rbl1 = bval ? *(const us8*)(nfl + bo + 8) : (us8)0;
    }

    for (int jt = js; jt < NJT; jt += JSPLIT) {
        f4 acc[2][8];
#pragma unroll
        for (int rf = 0; rf < 2; ++rf)
#pragma unroll
            for (int cf = 0; cf < 8; ++cf) acc[rf][cf] = (f4)0.0f;

        for (int ch = 0; ch < DIM / 32; ++ch) {
            int p = ch & 1;
            // write staged regs -> LDS buf p (prior readers of buf p fenced by barrier ch-1)
            *(us8*)(&S[p][0][lbase])     = rah0;  *(us8*)(&S[p][0][lbase + 8]) = rah1;
            *(us8*)(&S[p][1][lbase])     = ral0;  *(us8*)(&S[p][1][lbase + 8]) = ral1;
            *(us8*)(&S[p][2][lbase])     = rbh0;  *(us8*)(&S[p][2][lbase + 8]) = rbh1;
            *(us8*)(&S[p][3][lbase])     = rbl0;  *(us8*)(&S[p][3][lbase + 8]) = rbl1;
            __syncthreads();
            // issue next chunk's global loads (hide latency under MFMA)
            int nch = ch + 1, njt = jt;
            if (nch == DIM / 32) { nch = 0; njt = jt + JSPLIT; }
            if (njt < NJT) {
                size_t ao = abase + (size_t)nch * 32;
                rah0 = aval ? *(const us8*)(nfh + ao)     : (us8)0;
                rah1 = aval ? *(const us8*)(nfh + ao + 8) : (us8)0;
                ral0 = aval ? *(const us8*)(nfl + ao)     : (us8)0;
                ral1 = aval ? *(const us8*)(nfl + ao + 8) : (us8)0;
                int bgr = njt * 128 + srow;
                bool bval = bgr < N_ROWS;
                size_t bo = (size_t)bgr * DIM + skh * 16 + (size_t)nch * 32;
                rbh0 = bval ? *(const us8*)(nfh + bo)     : (us8)0;
                rbh1 = bval ? *(const us8*)(nfh + bo + 8) : (us8)0;
                rbl0 = bval ? *(const us8*)(nfl + bo)     : (us8)0;
                rbl1 = bval ? *(const us8*)(nfl + bo + 8) : (us8)0;
            }
            // compute from buf p
            s8b ah0 = *(const s8b*)(&S[p][0][(w*32 +  0 + c) * STR + g*8]);
            s8b ah1 = *(const s8b*)(&S[p][0][(w*32 + 16 + c) * STR + g*8]);
            s8b al0 = *(const s8b*)(&S[p][1][(w*32 +  0 + c) * STR + g*8]);
            s8b al1 = *(const s8b*)(&S[p][1][(w*32 + 16 + c) * STR + g*8]);
#pragma unroll
            for (int cf = 0; cf < 8; ++cf) {
                s8b bh = *(const s8b*)(&S[p][2][(cf*16 + c) * STR + g*8]);
                s8b bl = *(const s8b*)(&S[p][3][(cf*16 + c) * STR + g*8]);
                acc[0][cf] = __builtin_amdgcn_mfma_f32_16x16x32_bf16(bh, ah0, acc[0][cf], 0, 0, 0);
                acc[0][cf] = __builtin_amdgcn_mfma_f32_16x16x32_bf16(bl, ah0, acc[0][cf], 0, 0, 0);
                acc[0][cf] = __builtin_amdgcn_mfma_f32_16x16x32_bf16(bh, al0, acc[0][cf], 0, 0, 0);
                acc[1][cf] = __builtin_amdgcn_mfma_f32_16x16x32_bf16(bh, ah1, acc[1][cf], 0, 0, 0);
                acc[1][cf] = __builtin_amdgcn_mfma_f32_16x16x32_bf16(bl, ah1, acc[1][cf], 0, 0, 0);
                acc[1][cf] = __builtin_amdgcn_mfma_f32_16x16x32_bf16(bh, al1, acc[1][cf], 0, 0, 0);
            }
        }
        // in-register top-10 update (all static indices)
#pragma unroll
        for (int rf = 0; rf < 2; ++rf) {
            int row = m0 + w*32 + rf*16 + c;
#pragma unroll
            for (int cf = 0; cf < 8; ++cf) {
                f4 a = acc[rf][cf];
                int col0 = jt * 128 + cf*16 + g*4;
                float mx = fmaxf(fmaxf(a[0], a[1]), fmaxf(a[2], a[3]));
                if (mx > lv[rf][9]) {
#pragma unroll
                    for (int r = 0; r < 4; ++r) {
                        int col = col0 + r;
                        float val = a[r];
                        if (col < N_ROWS && col != row && val > lv[rf][9]) {
                            lv[rf][9] = val; li[rf][9] = col;
#pragma unroll
                            for (int u = 9; u > 0; --u) {
                                if (lv[rf][u] > lv[rf][u-1]) {
                                    float t2 = lv[rf][u]; lv[rf][u] = lv[rf][u-1]; lv[rf][u-1] = t2;
                                    int   t3 = li[rf][u]; li[rf][u] = li[rf][u-1]; li[rf][u-1] = t3;
                                }
                            }
                        }
                    }
                }
            }
        }
    }

    // merge across the 4 g-lanes sharing each row (butterfly xor 16,32), write partial list
#pragma unroll
    for (int rf = 0; rf < 2; ++rf) {
        int grow = m0 + w*32 + rf*16 + c;
#pragma unroll 1
        for (int sel = 0; sel < KNB; ++sel) {
            float cv = lv[rf][0]; int ci = li[rf][0];
            float bv = cv; int bi2 = ci;
            float ov = __shfl_xor(bv, 16, 64); int oi = __shfl_xor(bi2, 16, 64);
            if (ov > bv || (ov == bv && oi < bi2)) { bv = ov; bi2 = oi; }
            ov = __shfl_xor(bv, 32, 64); oi = __shfl_xor(bi2, 32, 64);
            if (ov > bv || (ov == bv && oi < bi2)) { bv = ov; bi2 = oi; }
            if (cv == bv && ci == bi2) {  // I won: pop my head
#pragma unroll
                for (int s = 0; s < 9; ++s) { lv[rf][s] = lv[rf][s+1]; li[rf][s] = li[rf][s+1]; }
                lv[rf][9] = -1e30f; li[rf][9] = 0x7fffffff;
            }
            if (g == 0 && grow < N_ROWS) {
                size_t o = ((size_t)js * N_ROWS + grow) * KNB + sel;
                pv[o] = bv; pi_[o] = bi2;
            }
        }
    }
}

// ---------------- classifier logits: bf16 hi/lo split MFMA, scaled by row norm ----------------
__global__ __launch_bounds__(256, 2) void gemm2_k(const unsigned short* __restrict__ nfh,
                                                  const unsigned short* __restrict__ nfl,
                                                  const unsigned short* __restrict__ cwh,
                                                  const unsigned short* __restrict__ cwl,
                                                  const float* __restrict__ rnorm,
                                                  float* __restrict__ logits) {
    __shared__ __align__(16) unsigned short S[2][4][128 * STR];
    int tid = threadIdx.x;
    int l = tid & 63, w = tid >> 6;
    int g = l >> 4, c = l & 15;
    int m0 = blockIdx.x * 128, n0 = blockIdx.y * 128;

    int srow = tid >> 1, skh = tid & 1;
    int agr = m0 + srow;
    bool aval = agr < N_ROWS;
    size_t abase = (size_t)agr * DIM + skh * 16;
    int bgr = n0 + srow;
    bool bval = bgr < NCLS;
    size_t bbase = (size_t)bgr * DIM + skh * 16;
    int lbase = srow * STR + skh * 16;

    us8 rah0, rah1, ral0, ral1, rbh0, rbh1, rbl0, rbl1;
    rah0 = aval ? *(const us8*)(nfh + abase)     : (us8)0;
    rah1 = aval ? *(const us8*)(nfh + abase + 8) : (us8)0;
    ral0 = aval ? *(const us8*)(nfl + abase)     : (us8)0;
    ral1 = aval ? *(const us8*)(nfl + abase + 8) : (us8)0;
    rbh0 = bval ? *(const us8*)(cwh + bbase)     : (us8)0;
    rbh1 = bval ? *(const us8*)(cwh + bbase + 8) : (us8)0;
    rbl0 = bval ? *(const us8*)(cwl + bbase)     : (us8)0;
    rbl1 = bval ? *(const us8*)(cwl + bbase + 8) : (us8)0;

    f4 acc[2][8];
#pragma unroll
    for (int rf = 0; rf < 2; ++rf)
#pragma unroll
        for (int cf = 0; cf < 8; ++cf) acc[rf][cf] = (f4)0.0f;

    for (int ch = 0; ch < DIM / 32; ++ch) {
        int p = ch & 1;
        *(us8*)(&S[p][0][lbase])     = rah0;  *(us8*)(&S[p][0][lbase + 8]) = rah1;
        *(us8*)(&S[p][1][lbase])     = ral0;  *(us8*)(&S[p][1][lbase + 8]) = ral1;
        *(us8*)(&S[p][2][lbase])     = rbh0;  *(us8*)(&S[p][2][lbase + 8]) = rbh1;
        *(us8*)(&S[p][3][lbase])     = rbl0;  *(us8*)(&S[p][3][lbase + 8]) = rbl1;
        __syncthreads();
        if (ch + 1 < DIM / 32) {
            size_t ao = abase + (size_t)(ch + 1) * 32;
            size_t bo = bbase + (size_t)(ch + 1) * 32;
            rah0 = aval ? *(const us8*)(nfh + ao)     : (us8)0;
            rah1 = aval ? *(const us8*)(nfh + ao + 8) : (us8)0;
            ral0 = aval ? *(const us8*)(nfl + ao)     : (us8)0;
            ral1 = aval ? *(const us8*)(nfl + ao + 8) : (us8)0;
            rbh0 = bval ? *(const us8*)(cwh + bo)     : (us8)0;
            rbh1 = bval ? *(const us8*)(cwh + bo + 8) : (us8)0;
            rbl0 = bval ? *(const us8*)(cwl + bo)     : (us8)0;
            rbl1 = bval ? *(const us8*)(cwl + bo + 8) : (us8)0;
        }
        s8b ah0 = *(const s8b*)(&S[p][0][(w*32 +  0 + c) * STR + g*8]);
        s8b ah1 = *(const s8b*)(&S[p][0][(w*32 + 16 + c) * STR + g*8]);
        s8b al0 = *(const s8b*)(&S[p][1][(w*32 +  0 + c) * STR + g*8]);
        s8b al1 = *(const s8b*)(&S[p][1][(w*32 + 16 + c) * STR + g*8]);
#pragma unroll
        for (int cf = 0; cf < 8; ++cf) {
            s8b bh = *(const s8b*)(&S[p][2][(cf*16 + c) * STR + g*8]);
            s8b bl = *(const s8b*)(&S[p][3][(cf*16 + c) * STR + g*8]);
            acc[0][cf] = __builtin_amdgcn_mfma_f32_16x16x32_bf16(bh, ah0, acc[0][cf], 0, 0, 0);
            acc[0][cf] = __builtin_amdgcn_mfma_f32_16x16x32_bf16(bl, ah0, acc[0][cf], 0, 0, 0);
            acc[0][cf] = __builtin_amdgcn_mfma_f32_16x16x32_bf16(bh, al0, acc[0][cf], 0, 0, 0);
            acc[1][cf] = __builtin_amdgcn_mfma_f32_16x16x32_bf16(bh, ah1, acc[1][cf], 0, 0, 0);
            acc[1][cf] = __builtin_amdgcn_mfma_f32_16x16x32_bf16(bl, ah1, acc[1][cf], 0, 0, 0);
            acc[1][cf] = __builtin_amdgcn_mfma_f32_16x16x32_bf16(bh, al1, acc[1][cf], 0, 0, 0);
        }
    }
#pragma unroll
    for (int rf = 0; rf < 2; ++rf) {
        int row = m0 + w*32 + rf*16 + c;
        if (row < N_ROWS) {
            float rn = rnorm[row];
#pragma unroll
            for (int cf = 0; cf < 8; ++cf) {
                f4 a = acc[rf][cf];
#pragma unroll
                for (int r = 0; r < 4; ++r) {
                    int col = n0 + cf*16 + g*4 + r;
                    if (col < NCLS) logits[(size_t)row * NCLS + col] = a[r] * rn;
                }
            }
        }
    }
}

// ---------------- row softmax (C=1000) ----------------
__global__ __launch_bounds__(256) void softmax_k(const float* __restrict__ logits,
                                                 float* __restrict__ Y) {
    int row = blockIdx.x;
    const float* src = logits + (size_t)row * NCLS;
    __shared__ float sl[NCLS];
    __shared__ float red[4];
    int t = threadIdx.x;
    float mx = -1e30f;
    for (int cc = t; cc < NCLS; cc += 256) { float x = src[cc]; sl[cc] = x; mx = fmaxf(mx, x); }
#pragma unroll
    for (int m = 1; m < 64; m <<= 1) mx = fmaxf(mx, __shfl_xor(mx, m, 64));
    if ((t & 63) == 0) red[t >> 6] = mx;
    __syncthreads();
    mx = fmaxf(fmaxf(red[0], red[1]), fmaxf(red[2], red[3]));
    float sum = 0.f;
    for (int cc = t; cc < NCLS; cc += 256) { float e = expf(sl[cc] - mx); sl[cc] = e; sum += e; }
#pragma unroll
    for (int m = 1; m < 64; m <<= 1) sum += __shfl_xor(sum, m, 64);
    __syncthreads();
    if ((t & 63) == 0) red[t >> 6] = sum;
    __syncthreads();
    float inv = 1.0f / (red[0] + red[1] + red[2] + red[3]);
    float* dst = Y + (size_t)row * NCLS;
    for (int cc = t; cc < NCLS; cc += 256) dst[cc] = sl[cc] * inv;
}

// ---------------- final merge of JSPLIT partial top-10 lists ----------------
__global__ void topmerge_k(float* __restrict__ pv, const int* __restrict__ pi_,
                           float* __restrict__ tv, int* __restrict__ ti_) {
    int row = blockIdx.x * blockDim.x + threadIdx.x;
    if (row >= N_ROWS) return;
    for (int sel = 0; sel < KNB; ++sel) {
        float best = -1e30f; long bslot = -1;
        for (int js = 0; js < JSPLIT; ++js) {
            size_t base = ((size_t)js * N_ROWS + row) * KNB;
            for (int k = 0; k < KNB; ++k) {
                float v = pv[base + k];
                if (v > best) { best = v; bslot = (long)(base + k); }
            }
        }
        tv[(size_t)row * KNB + sel] = best;
        ti_[(size_t)row * KNB + sel] = pi_[bslot];
        pv[bslot] = -1e30f;
    }
}

// ---------------- graph build ----------------
__global__ void edgecount_k(const float* __restrict__ tv, const int* __restrict__ ti_,
                            float* __restrict__ deg, int* __restrict__ cnt) {
    int e = blockIdx.x * blockDim.x + threadIdx.x;
    if (e >= N_ROWS * KNB) return;
    int i = e / KNB;
    int j = ti_[e];
    float v = fmaxf(tv[e], 0.f);
    float wv = 0.5f * v * v * v;
    atomicAdd(&deg[i], wv);
    atomicAdd(&deg[j], wv);
    atomicAdd(&cnt[i], 1);
    atomicAdd(&cnt[j], 1);
}

__global__ __launch_bounds__(1024) void scan_k(const int* __restrict__ cnt,
                                               int* __restrict__ rowptr,
                                               int* __restrict__ cur,
                                               const float* __restrict__ deg,
                                               float* __restrict__ dis) {
    __shared__ int sb[1024];
    int t = threadIdx.x;
    int carry = 0;
    for (int base = 0; base < N_ROWS; base += 1024) {
        int idx = base + t;
        int x = (idx < N_ROWS) ? cnt[idx] : 0;
        sb[t] = x;
        __syncthreads();
        for (int offc = 1; offc < 1024; offc <<= 1) {
            int add = (t >= offc) ? sb[t - offc] : 0;
            __syncthreads();
            sb[t] += add;
            __syncthreads();
        }
        int incl = sb[t];
        int tot = sb[1023];
        if (idx < N_ROWS) {
            rowptr[idx + 1] = carry + incl;
            cur[idx] = carry + incl - x;
            if (idx == 0) rowptr[0] = 0;
            dis[idx] = 1.0f / (sqrtf(deg[idx] + EPSV));
        }
        __syncthreads();
        carry += tot;
    }
}

__global__ void fill_k(const float* __restrict__ tv, const int* __restrict__ ti_,
                       const float* __restrict__ dis, int* __restrict__ cur,
                       int* __restrict__ cols, float* __restrict__ wts) {
    int e = blockIdx.x * blockDim.x + threadIdx.x;
    if (e >= N_ROWS * KNB) return;
    int i = e / KNB;
    int j = ti_[e];
    float v = fmaxf(tv[e], 0.f);
    float wv = 0.5f * v * v * v;
    float s = 0.99f * wv * dis[i] * dis[j];   // ALPHA folded into edge weight
    int p1 = atomicAdd(&cur[i], 1); cols[p1] = j; wts[p1] = s;
    int p2 = atomicAdd(&cur[j], 1); cols[p2] = i; wts[p2] = s;
}

// ---------------- sparse propagation step ----------------
__global__ __launch_bounds__(256) void spmv_k(const int* __restrict__ rowptr,
                                              const int* __restrict__ cols,
                                              const float* __restrict__ wts,
                                              const float* __restrict__ Zin,
                                              const float* __restrict__ Y,
                                              float* __restrict__ Zout) {
    int i = blockIdx.x;
    int b = rowptr[i], e = rowptr[i + 1];
    int nnz = e - b;
    __shared__ int   cs[MAXE];
    __shared__ float wsh[MAXE];
    int nl = min(nnz, MAXE);
    for (int t = threadIdx.x; t < nl; t += 256) { cs[t] = cols[b + t]; wsh[t] = wts[b + t]; }
    __syncthreads();
    const float beta = (float)(1.0 - 0.99);
    for (int cc = threadIdx.x; cc < NCLS; cc += 256) {
        float acc = beta * Y[(size_t)i * NCLS + cc];
        for (int k = 0; k < nl; ++k) acc += wsh[k] * Zin[(size_t)cs[k] * NCLS + cc];
        for (int k = MAXE; k < nnz; ++k) acc += wts[b + k] * Zin[(size_t)cols[b + k] * NCLS + cc];
        Zout[(size_t)i * NCLS + cc] = acc;
    }
}

extern "C" void kernel_launch(void* const* d_in, const int* in_sizes, int n_in,
                              void* d_out, int out_size, void* d_ws, size_t ws_size,
                              hipStream_t stream) {
    const float* feat = (const float*)d_in[0];
    const float* cw   = (const float*)d_in[1];
    float* out = (float*)d_out;
    char* ws = (char*)d_ws;
    size_t off = 0;
    auto alloc = [&](size_t b) { size_t o = off; off = (off + b + 255) & ~(size_t)255; return o; };
    unsigned short* nfh = (unsigned short*)(ws + alloc((size_t)N_ROWS * DIM * 2));
    unsigned short* nfl = (unsigned short*)(ws + alloc((size_t)N_ROWS * DIM * 2));
    unsigned short* cwh = (unsigned short*)(ws + alloc((size_t)NCLS * DIM * 2));
    unsigned short* cwl = (unsigned short*)(ws + alloc((size_t)NCLS * DIM * 2));
    float* rnorm = (float*)(ws + alloc(N_ROWS * 4));
    float* ZA   = (float*)(ws + alloc((size_t)N_ROWS * NCLS * 4));   // logits, then Z ping buffer
    float* Y    = (float*)(ws + alloc((size_t)N_ROWS * NCLS * 4));
    float* pv   = (float*)(ws + alloc((size_t)JSPLIT * N_ROWS * KNB * 4));
    int*   pi_  = (int*)  (ws + alloc((size_t)JSPLIT * N_ROWS * KNB * 4));
    float* tv   = (float*)(ws + alloc((size_t)N_ROWS * KNB * 4));
    int*   ti_  = (int*)  (ws + alloc((size_t)N_ROWS * KNB * 4));
    float* deg  = (float*)(ws + alloc(N_ROWS * 4));
    int*   cnt  = (int*)  (ws + alloc(N_ROWS * 4));
    int*   rowptr = (int*)(ws + alloc((N_ROWS + 1) * 4));
    int*   cur  = (int*)  (ws + alloc(N_ROWS * 4));
    float* dis  = (float*)(ws + alloc(N_ROWS * 4));
    int*   cols = (int*)  (ws + alloc((size_t)2 * N_ROWS * KNB * 4));
    float* wts  = (float*)(ws + alloc((size_t)2 * N_ROWS * KNB * 4));
    if (off > ws_size) return;

    hipMemsetAsync(deg, 0, N_ROWS * 4, stream);
    hipMemsetAsync(cnt, 0, N_ROWS * 4, stream);

    rownorm2_k<<<N_ROWS, 192, 0, stream>>>(feat, nfh, nfl, rnorm);
    split_k<<<(NCLS * DIM / 4 + 255) / 256, 256, 0, stream>>>(cw, cwh, cwl, NCLS * DIM / 4);

    dim3 gl(NRT, NCT);
    gemm2_k<<<gl, 256, 0, stream>>>(nfh, nfl, cwh, cwl, rnorm, ZA);
    softmax_k<<<N_ROWS, 256, 0, stream>>>(ZA, Y);

    simtopk_k<<<NRT * JSPLIT, 256, 0, stream>>>(nfh, nfl, pv, pi_);
    topmerge_k<<<(N_ROWS + 255) / 256, 256, 0, stream>>>(pv, pi_, tv, ti_);

    edgecount_k<<<(N_ROWS * KNB + 255) / 256, 256, 0, stream>>>(tv, ti_, deg, cnt);
    scan_k<<<1, 1024, 0, stream>>>(cnt, rowptr, cur, deg, dis);
    fill_k<<<(N_ROWS * KNB + 255) / 256, 256, 0, stream>>>(tv, ti_, dis, cur, cols, wts);

    const float* zin = Y;
    for (int it = 0; it < NITER; ++it) {
        float* zout = (it & 1) ? out : ZA;     // it=19 (odd) lands on d_out
        spmv_k<<<N_ROWS, 256, 0, stream>>>(rowptr, cols, wts, zin, Y, zout);
        zin = zout;
    }
}